// Round 10
// baseline (230.417 us; speedup 1.0000x reference)
//
#include <hip/hip_runtime.h>

// Problem constants (fixed by setup_inputs: bs=8, N=M=4096, C=128)
#define BS 8
#define NN 4096
#define MM 4096
#define CC 128
#define XT 128            // x rows per block
#define MT 128            // y rows per m-tile
#define MH 2048           // cols per block
#define NMT (MH / MT)     // 16 m-tiles per block
#define NXT (NN / XT)     // 32 x-tiles
#define NBLK (NXT * (MM / MH) * BS)   // 512 ch_tile blocks

#define FINF_BITS 0x7F800000u

typedef __attribute__((ext_vector_type(8))) short bf16x8;
typedef __attribute__((ext_vector_type(4))) float f32x4;

// RNE fp32 -> bf16 (inputs are finite normals)
__device__ inline ushort f2bf(float f) {
    unsigned u = __float_as_uint(f);
    unsigned r = (u + 0x7FFFu + ((u >> 16) & 1u)) >> 16;
    return (ushort)r;
}

// ---------------------------------------------------------------------------
// y-prep: fp32->bf16 copy of set2 only + exact fp32 y norms + rowmin/colmin
// init + done=0 + out=0. (x is converted in-kernel by ch_tile now.)
// One float4 of y per thread.
// ---------------------------------------------------------------------------
__global__ void ch_prep(const float* __restrict__ y,
                        ushort* __restrict__ y16, float* __restrict__ yn,
                        unsigned* __restrict__ rowmin, unsigned* __restrict__ colmin,
                        unsigned* __restrict__ done, float* __restrict__ out) {
    int gid = blockIdx.x * blockDim.x + threadIdx.x;
    size_t i = (size_t)gid * 4;

    float4 w = *(const float4*)(y + i);
    ushort4 p;
    p.x = f2bf(w.x); p.y = f2bf(w.y); p.z = f2bf(w.z); p.w = f2bf(w.w);
    *(ushort4*)(y16 + i) = p;
    float sy = w.x * w.x + w.y * w.y + w.z * w.z + w.w * w.w;

    // 32 consecutive lanes cover one row (128 floats / 4)
#pragma unroll
    for (int mask = 1; mask <= 16; mask <<= 1)
        sy += __shfl_xor(sy, mask, 64);
    if ((threadIdx.x & 31) == 0)
        yn[gid >> 5] = sy;

    if (gid < BS * NN) rowmin[gid] = FINF_BITS;
    if (gid < BS * MM) colmin[gid] = FINF_BITS;
    if (gid == 0) { *done = 0u; out[0] = 0.0f; }
}

// ---------------------------------------------------------------------------
// main kernel (R10 = R8 core + in-kernel x conversion + fused finalize):
//  - 512 thr / 8 waves = 2 row-halves x 4 col-quarters of a 128x128 tile;
//    per-wave acc = 4x2 MFMAs (32 AGPR).
//  - x-tile converted fp32->bf16 DURING the swizzled LDS staging (no global
//    x16 buffer, no x pass in prep); x norms computed in-LDS at the same time.
//  - y fragments direct from global (L2-resident). No barriers in m-loop.
//  - Row d^2 mins persist in regs; col mins via LDS atomicMin; one global
//    atomicMin flush at block end. sqrt deferred.
//  - LAST block (device-scope counter + threadfence) runs the weighted
//    sqrt-sum finalize in-block: no third kernel launch.
// ---------------------------------------------------------------------------
__global__ __launch_bounds__(512) void ch_tile(
    const float* __restrict__ Xf, const ushort* __restrict__ Y,
    const float* __restrict__ yn,
    unsigned* __restrict__ rowmin, unsigned* __restrict__ colmin,
    const float* __restrict__ w1, const float* __restrict__ w2,
    unsigned* __restrict__ done, float* __restrict__ out) {

    __shared__ ushort xs[XT * CC];     // 32 KB, chunk-swizzled
    __shared__ unsigned coltile[MH];   // 8 KB
    __shared__ unsigned rowtile[XT];   // 0.5 KB
    __shared__ float xnorm[XT];        // 0.5 KB

    const int b  = blockIdx.z;
    const int xt = blockIdx.x;         // 0..31
    const int mh = blockIdx.y;         // 0..1
    const int n0 = xt * XT;
    const int m0 = mh * MH;
    const int tid  = threadIdx.x;
    const int wave = tid >> 6;         // 0..7
    const int lane = tid & 63;
    const int lc   = lane & 15;        // A/B row, C col
    const int quad = lane >> 4;        // k-chunk, C row group
    const int wm = wave >> 2;          // row half (0/1)
    const int wn = wave & 3;           // col quarter (0..3)

    // ---- stage x tile: fp32 load -> bf16 -> swizzled LDS; norms too ----
    const float* Xb = Xf + ((size_t)b * NN + n0) * CC;
    {
        float psum[4];
#pragma unroll
        for (int s = 0; s < 4; ++s) {
            int flat = s * 512 + tid;  // 2048 chunks = 128 rows x 16
            int r = flat >> 4, c = flat & 15;
            float4 v0 = *(const float4*)(Xb + (size_t)r * CC + c * 8);
            float4 v1 = *(const float4*)(Xb + (size_t)r * CC + c * 8 + 4);
            ushort h[8] = {f2bf(v0.x), f2bf(v0.y), f2bf(v0.z), f2bf(v0.w),
                           f2bf(v1.x), f2bf(v1.y), f2bf(v1.z), f2bf(v1.w)};
            *(bf16x8*)(xs + r * CC + (c ^ (r & 7)) * 8) = *(bf16x8*)h;
            psum[s] = v0.x * v0.x + v0.y * v0.y + v0.z * v0.z + v0.w * v0.w +
                      v1.x * v1.x + v1.y * v1.y + v1.z * v1.z + v1.w * v1.w;
        }
        // 16 lanes (same tid>>4) share each row: reduce partials
#pragma unroll
        for (int mask = 1; mask <= 8; mask <<= 1)
#pragma unroll
            for (int s = 0; s < 4; ++s)
                psum[s] += __shfl_xor(psum[s], mask, 64);
        if ((tid & 15) == 0) {
#pragma unroll
            for (int s = 0; s < 4; ++s)
                xnorm[s * 32 + (tid >> 4)] = psum[s];
        }
    }
    for (int c2 = tid; c2 < MH; c2 += 512) coltile[c2] = FINF_BITS;
    if (tid < XT) rowtile[tid] = FINF_BITS;
    __syncthreads();

    // persistent x norms for this wave's 64 rows
    float xnr[4][4];
#pragma unroll
    for (int i = 0; i < 4; ++i) {
        float4 t = *(const float4*)(&xnorm[wm * 64 + i * 16 + quad * 4]);
        xnr[i][0] = t.x; xnr[i][1] = t.y; xnr[i][2] = t.z; xnr[i][3] = t.w;
    }
    float rm[4][4];
#pragma unroll
    for (int i = 0; i < 4; ++i)
#pragma unroll
        for (int r = 0; r < 4; ++r) rm[i][r] = __builtin_inff();

    const ushort* Yb  = Y + ((size_t)b * MM + m0) * CC;
    const float*  ynb = yn + (size_t)b * MM + m0;
    const int xrow = (wm * 64 + lc) * CC;
    const int xsw  = lc & 7;

#pragma unroll 1
    for (int mt = 0; mt < NMT; ++mt) {
        const ushort* Ymt = Yb + (size_t)(mt * MT + wn * 32 + lc) * CC + quad * 8;

        float ynr[2];
#pragma unroll
        for (int j = 0; j < 2; ++j)
            ynr[j] = ynb[mt * MT + wn * 32 + j * 16 + lc];

        f32x4 acc[4][2];
        const f32x4 z = {0.f, 0.f, 0.f, 0.f};
#pragma unroll
        for (int kt = 0; kt < 4; ++kt) {
            bf16x8 af[4], yf[2];
            const int cs = ((kt * 4 + quad) ^ xsw) * 8;
#pragma unroll
            for (int j = 0; j < 2; ++j)
                yf[j] = *(const bf16x8*)(Ymt + (size_t)j * 16 * CC + kt * 32);
#pragma unroll
            for (int i = 0; i < 4; ++i)
                af[i] = *(const bf16x8*)(xs + xrow + i * 16 * CC + cs);
#pragma unroll
            for (int j = 0; j < 2; ++j)
#pragma unroll
                for (int i = 0; i < 4; ++i)
                    acc[i][j] = __builtin_amdgcn_mfma_f32_16x16x32_bf16(
                        af[i], yf[j], (kt == 0) ? z : acc[i][j], 0, 0, 0);
        }

        // ---- epilogue: d^2 mins (sqrt/clamp deferred) ----
        float cmv[2];
#pragma unroll
        for (int j = 0; j < 2; ++j) cmv[j] = __builtin_inff();

#pragma unroll
        for (int i = 0; i < 4; ++i) {
#pragma unroll
            for (int j = 0; j < 2; ++j) {
                f32x4 a = acc[i][j];
#pragma unroll
                for (int r = 0; r < 4; ++r) {
                    float d2 = xnr[i][r] + fmaf(-2.0f, a[r], ynr[j]);
                    rm[i][r] = fminf(rm[i][r], d2);
                    cmv[j]   = fminf(cmv[j], d2);
                }
            }
        }

        // col reduce across quads, then LDS atomic
#pragma unroll
        for (int mask = 16; mask <= 32; mask <<= 1)
#pragma unroll
            for (int j = 0; j < 2; ++j)
                cmv[j] = fminf(cmv[j], __shfl_xor(cmv[j], mask, 64));
        if (quad == 0) {
#pragma unroll
            for (int j = 0; j < 2; ++j)
                atomicMin(&coltile[mt * MT + wn * 32 + j * 16 + lc],
                          __float_as_uint(fmaxf(cmv[j], 0.0f)));
        }
    }

    // ---- row mins: reduce across the 16 lc lanes, LDS atomic once ----
#pragma unroll
    for (int mask = 1; mask <= 8; mask <<= 1)
#pragma unroll
        for (int i = 0; i < 4; ++i)
#pragma unroll
            for (int r = 0; r < 4; ++r)
                rm[i][r] = fminf(rm[i][r], __shfl_xor(rm[i][r], mask, 64));
    if (lc == 0) {
#pragma unroll
        for (int i = 0; i < 4; ++i)
#pragma unroll
            for (int r = 0; r < 4; ++r)
                atomicMin(&rowtile[wm * 64 + i * 16 + quad * 4 + r],
                          __float_as_uint(fmaxf(rm[i][r], 0.0f)));
    }

    // ---- flush tile minima with global atomics ----
    __syncthreads();
    if (tid < XT)
        atomicMin(&rowmin[(size_t)b * NN + n0 + tid], rowtile[tid]);
    for (int c2 = tid; c2 < MH; c2 += 512)
        atomicMin(&colmin[(size_t)b * MM + m0 + c2], coltile[c2]);

    // ---- fused finalize: last block does the weighted sqrt-sum ----
    __threadfence();                       // make our atomics visible
    __syncthreads();
    __shared__ unsigned isLast;
    if (tid == 0) isLast = (atomicAdd(done, 1u) == NBLK - 1) ? 1u : 0u;
    __syncthreads();
    if (isLast) {
        __threadfence();                   // acquire: see all blocks' mins
        float s = 0.f;
        for (int idx = tid; idx < BS * NN; idx += 512)
            s += w1[idx] * sqrtf(__uint_as_float(rowmin[idx])) +
                 w2[idx] * sqrtf(__uint_as_float(colmin[idx]));
#pragma unroll
        for (int off = 32; off > 0; off >>= 1) s += __shfl_down(s, off, 64);
        __shared__ float ls[8];
        if (lane == 0) ls[wave] = s;
        __syncthreads();
        if (tid == 0) {
            float t = 0.f;
#pragma unroll
            for (int k = 0; k < 8; ++k) t += ls[k];
            out[0] = 0.5f * t;
        }
    }
}

extern "C" void kernel_launch(void* const* d_in, const int* in_sizes, int n_in,
                              void* d_out, int out_size, void* d_ws, size_t ws_size,
                              hipStream_t stream) {
    const float* set1 = (const float*)d_in[0];
    const float* set2 = (const float*)d_in[1];
    const float* w1   = (const float*)d_in[2];
    const float* w2   = (const float*)d_in[3];
    float* out = (float*)d_out;

    // workspace layout (~8.5 MiB)
    ushort*   y16    = (ushort*)d_ws;                        // BS*MM*CC bf16 (8 MB)
    float*    yn     = (float*)(y16 + (size_t)BS * MM * CC); // 128 KB
    unsigned* rowmin = (unsigned*)(yn + BS * MM);            // 128 KB (d^2 bits)
    unsigned* colmin = rowmin + BS * NN;                     // 128 KB (d^2 bits)
    unsigned* done   = colmin + BS * MM;                     // 1

    ch_prep<<<BS * MM * CC / 4 / 256, 256, 0, stream>>>(
        set2, y16, yn, rowmin, colmin, done, out);

    dim3 grid(NXT, MM / MH, BS);
    ch_tile<<<grid, 512, 0, stream>>>(set1, y16, yn, rowmin, colmin,
                                      w1, w2, done, out);
}